// Round 1
// baseline (504.696 us; speedup 1.0000x reference)
//
#include <hip/hip_runtime.h>
#include <hip/hip_bf16.h>

// Problem constants: T=512, B=8, E=1024, H=32, HD=32
typedef __attribute__((ext_vector_type(8))) short short8;
typedef __attribute__((ext_vector_type(4))) float f32x4;

__device__ __forceinline__ f32x4 mfma16(short8 a, short8 b, f32x4 c) {
    return __builtin_amdgcn_mfma_f32_16x16x32_bf16(a, b, c, 0, 0, 0);
}

__device__ __forceinline__ unsigned pk2bf(float lo, float hi) {
    __hip_bfloat162 h2;
    h2.x = __float2bfloat16(lo);
    h2.y = __float2bfloat16(hi);
    unsigned u;
    __builtin_memcpy(&u, &h2, 4);
    return u;
}
__device__ __forceinline__ float bflo(unsigned u) {
    unsigned v = u << 16; float f; __builtin_memcpy(&f, &v, 4); return f;
}
__device__ __forceinline__ float bfhi(unsigned u) {
    unsigned v = u & 0xffff0000u; float f; __builtin_memcpy(&f, &v, 4); return f;
}

// ---------------------------------------------------------------------------
// Kernel 1: C[m=(b*512+t)][n=0..1087] = x @ [Wq|Wk|Wv]^T ; x[b,t,:] = query[t,b,:]
// outputs: q_bf[b,t,h] (scaled, bf16), k_bf[b,t,h] (bf16), v_t[b,h,d,t] (bf16)
// tile 128x64, BK=32, 4 waves
// ---------------------------------------------------------------------------
__global__ __launch_bounds__(256) void prep_kernel(
    const float* __restrict__ query,
    const float* __restrict__ Wq, const float* __restrict__ bq,
    const float* __restrict__ Wk, const float* __restrict__ bk,
    const float* __restrict__ Wv, const float* __restrict__ bv,
    __hip_bfloat16* __restrict__ q_bf,
    __hip_bfloat16* __restrict__ k_bf,
    __hip_bfloat16* __restrict__ v_t)
{
    __shared__ unsigned lA[128 * 20];  // 128 rows x 40 bf16 (80B rows, 2-way-free banks)
    __shared__ unsigned lB[64 * 20];
    const int m0 = blockIdx.x * 128;
    const int n0 = blockIdx.y * 64;
    const int tid = threadIdx.x;
    const int lane = tid & 63, w = tid >> 6;
    const int g = lane >> 4, li = lane & 15;
    const int mw = w >> 1, nw = w & 1;

    f32x4 acc[4][2];
    const f32x4 zero4 = {0.f, 0.f, 0.f, 0.f};
    for (int mf = 0; mf < 4; mf++)
        for (int nf = 0; nf < 2; nf++) acc[mf][nf] = zero4;

    // A staging assignment: 2 threads per row, 16 f32 each
    const int ar = tid >> 1, ah = tid & 1;
    const int am = m0 + ar;
    const int ab_ = am >> 9, at = am & 511;
    const float* asrc = query + (size_t)(at * 8 + ab_) * 1024;
    // B staging: 4 threads per row, 8 f32 each
    const int bn = tid >> 2, bq4 = tid & 3;
    const int bng = n0 + bn;
    const float* wrow = (bng < 32) ? (Wq + (size_t)bng * 1024)
                      : (bng < 64) ? (Wk + (size_t)(bng - 32) * 1024)
                                   : (Wv + (size_t)(bng - 64) * 1024);

    for (int k0 = 0; k0 < 1024; k0 += 32) {
        {
            const float4* s = (const float4*)(asrc + k0 + ah * 16);
            float4 v0 = s[0], v1 = s[1], v2 = s[2], v3 = s[3];
            unsigned* d = lA + ar * 20 + ah * 8;
            d[0] = pk2bf(v0.x, v0.y); d[1] = pk2bf(v0.z, v0.w);
            d[2] = pk2bf(v1.x, v1.y); d[3] = pk2bf(v1.z, v1.w);
            d[4] = pk2bf(v2.x, v2.y); d[5] = pk2bf(v2.z, v2.w);
            d[6] = pk2bf(v3.x, v3.y); d[7] = pk2bf(v3.z, v3.w);
        }
        {
            const float4* s = (const float4*)(wrow + k0 + bq4 * 8);
            float4 v0 = s[0], v1 = s[1];
            unsigned* d = lB + bn * 20 + bq4 * 4;
            d[0] = pk2bf(v0.x, v0.y); d[1] = pk2bf(v0.z, v0.w);
            d[2] = pk2bf(v1.x, v1.y); d[3] = pk2bf(v1.z, v1.w);
        }
        __syncthreads();
        short8 afr[4], bfr[2];
        #pragma unroll
        for (int mf = 0; mf < 4; mf++)
            afr[mf] = *(const short8*)((const char*)lA + (mw * 64 + mf * 16 + li) * 80 + g * 16);
        #pragma unroll
        for (int nf = 0; nf < 2; nf++)
            bfr[nf] = *(const short8*)((const char*)lB + (nw * 32 + nf * 16 + li) * 80 + g * 16);
        #pragma unroll
        for (int mf = 0; mf < 4; mf++)
            #pragma unroll
            for (int nf = 0; nf < 2; nf++)
                acc[mf][nf] = mfma16(afr[mf], bfr[nf], acc[mf][nf]);
        __syncthreads();
    }

    const float scaling = 0.17677669529663687f;  // 32^-0.5
    #pragma unroll
    for (int mf = 0; mf < 4; mf++) {
        #pragma unroll
        for (int nf = 0; nf < 2; nf++) {
            const int ng = n0 + nw * 32 + nf * 16 + li;
            const int mbase = m0 + mw * 64 + mf * 16 + 4 * g;
            f32x4 a = acc[mf][nf];
            if (ng < 32) {
                const float bias = bq[ng];
                for (int r = 0; r < 4; r++)
                    q_bf[(size_t)(mbase + r) * 32 + ng] = __float2bfloat16((a[r] + bias) * scaling);
            } else if (ng < 64) {
                const float bias = bk[ng - 32];
                for (int r = 0; r < 4; r++)
                    k_bf[(size_t)(mbase + r) * 32 + (ng - 32)] = __float2bfloat16(a[r] + bias);
            } else {
                const int e = ng - 64;
                const float bias = bv[e];
                const int h = e >> 5, d = e & 31;
                const int bb2 = mbase >> 9, t0 = mbase & 511;
                uint2 p;
                p.x = pk2bf(a[0] + bias, a[1] + bias);
                p.y = pk2bf(a[2] + bias, a[3] + bias);
                *(uint2*)(v_t + (size_t)((bb2 * 32 + h) * 32 + d) * 512 + t0) = p;
            }
        }
    }
}

// ---------------------------------------------------------------------------
// Kernel 2: fused rank-1 logits + Wt head-mix + bias + softmax(no-max) + PV
// grid 256 (one WG per (b, 16-row i-tile)), 512 threads (8 waves)
// wave w: p-phase owns i in {2w,2w+1}; PV-phase owns h in [4w,4w+4)
// ---------------------------------------------------------------------------
__global__ __launch_bounds__(512, 2) void attn_kernel(
    const float* __restrict__ attn_bias,
    const float* __restrict__ Wt,
    const __hip_bfloat16* __restrict__ q_bf,
    const __hip_bfloat16* __restrict__ k_bf,
    const __hip_bfloat16* __restrict__ v_t,
    __hip_bfloat16* __restrict__ out_pre)
{
    __shared__ uint4 p_lds4[4096];  // 64KB: p[i][h][j] bf16, XOR-swizzled j-chunks
    __shared__ float s_buf[16][32];
    char* p_lds = (char*)p_lds4;

    int wg = blockIdx.x;
    wg = (wg & 7) * 32 + (wg >> 3);  // XCD x owns batch x entirely (256 = 8*32)
    const int b = wg >> 5, i0 = (wg & 31) * 16;
    const int tid = threadIdx.x;
    const int w = tid >> 6, lane = tid & 63;
    const int g = lane >> 4, li = lane & 15;

    // Wt B-frags: B[k=h'][n=h] = Wt[h][h']  (lane: n=li+16hb, k=8g+t) -> contiguous
    short8 wfrag[2];
    #pragma unroll
    for (int hb = 0; hb < 2; hb++) {
        const float4* s = (const float4*)(Wt + (li + 16 * hb) * 32 + 8 * g);
        float4 c0 = s[0], c1 = s[1];
        unsigned u[4] = { pk2bf(c0.x, c0.y), pk2bf(c0.z, c0.w),
                          pk2bf(c1.x, c1.y), pk2bf(c1.z, c1.w) };
        __builtin_memcpy(&wfrag[hb], u, 16);
    }
    // q for this wave's two i's (unpacked to f32)
    float qf[2][8];
    #pragma unroll
    for (int i2 = 0; i2 < 2; i2++) {
        const unsigned* s = (const unsigned*)(q_bf + (size_t)(b * 512 + i0 + 2 * w + i2) * 32 + 8 * g);
        #pragma unroll
        for (int t = 0; t < 4; t++) {
            unsigned u = s[t];
            qf[i2][2 * t] = bflo(u);
            qf[i2][2 * t + 1] = bfhi(u);
        }
    }

    const f32x4 zero4 = {0.f, 0.f, 0.f, 0.f};
    f32x4 accpv[4][2];
    for (int h4 = 0; h4 < 4; h4++)
        for (int ab = 0; ab < 2; ab++) accpv[h4][ab] = zero4;
    float sp[2][2] = {{0.f, 0.f}, {0.f, 0.f}};

    for (int it = 0; it < 8; it++) {
        const int j0 = it * 64;
        // bias loads (j-contiguous dwordx4), issued up front
        float4 bias_r[2][4][2];
        #pragma unroll
        for (int i2 = 0; i2 < 2; i2++)
            #pragma unroll
            for (int jb = 0; jb < 4; jb++)
                #pragma unroll
                for (int hb = 0; hb < 2; hb++)
                    bias_r[i2][jb][hb] = *(const float4*)(attn_bias
                        + (size_t)((b * 32 + (li + 16 * hb)) * 512 + (i0 + 2 * w + i2)) * 512
                        + j0 + jb * 16 + 4 * g);
        // k tile (rows = j, coalesced 16B/lane)
        float kf[4][8];
        #pragma unroll
        for (int jb = 0; jb < 4; jb++) {
            const unsigned* s = (const unsigned*)(k_bf + (size_t)(b * 512 + j0 + jb * 16 + li) * 32 + 8 * g);
            #pragma unroll
            for (int t = 0; t < 4; t++) {
                unsigned u = s[t];
                kf[jb][2 * t] = bflo(u);
                kf[jb][2 * t + 1] = bfhi(u);
            }
        }
        // P = q*k -> MFMA with Wt^T -> +bias -> exp -> pack to LDS
        #pragma unroll
        for (int i2 = 0; i2 < 2; i2++) {
            const int i = 2 * w + i2;
            #pragma unroll
            for (int jb = 0; jb < 4; jb++) {
                unsigned au[4];
                #pragma unroll
                for (int t = 0; t < 4; t++)
                    au[t] = pk2bf(qf[i2][2 * t] * kf[jb][2 * t], qf[i2][2 * t + 1] * kf[jb][2 * t + 1]);
                short8 af;
                __builtin_memcpy(&af, au, 16);
                #pragma unroll
                for (int hb = 0; hb < 2; hb++) {
                    f32x4 dmix = mfma16(af, wfrag[hb], zero4);
                    float4 bv4 = bias_r[i2][jb][hb];
                    float p0 = __expf(dmix[0] + bv4.x);
                    float p1 = __expf(dmix[1] + bv4.y);
                    float p2 = __expf(dmix[2] + bv4.z);
                    float p3 = __expf(dmix[3] + bv4.w);
                    sp[i2][hb] += (p0 + p1) + (p2 + p3);
                    uint2 pw;
                    pw.x = pk2bf(p0, p1);
                    pw.y = pk2bf(p2, p3);
                    const int h = li + 16 * hb;
                    const int jbyte = jb * 32 + 8 * g;  // byte off of j-chunk (j = jb*16+4g+r)
                    *(uint2*)(p_lds + i * 4096 + h * 128 + (jbyte ^ (((i ^ h) & 7) << 4))) = pw;
                }
            }
        }
        __syncthreads();
        // PV: out^T = v_t * p  (D[m=d][n=i], contraction over j)
        #pragma unroll
        for (int h4 = 0; h4 < 4; h4++) {
            const int h = 4 * w + h4;
            short8 pfr[2];
            #pragma unroll
            for (int kb = 0; kb < 2; kb++) {
                const int jbyte = kb * 64 + 16 * g;
                pfr[kb] = *(const short8*)(p_lds + li * 4096 + h * 128 + (jbyte ^ (((li ^ h) & 7) << 4)));
            }
            #pragma unroll
            for (int ab = 0; ab < 2; ab++) {
                #pragma unroll
                for (int kb = 0; kb < 2; kb++) {
                    const short8 va = *(const short8*)(v_t
                        + (size_t)((b * 32 + h) * 32 + li + 16 * ab) * 512 + j0 + kb * 32 + 8 * g);
                    accpv[h4][ab] = mfma16(va, pfr[kb], accpv[h4][ab]);
                }
            }
        }
        __syncthreads();
    }

    // finalize s (reduce across the 4 lane-groups) and normalize O
    #pragma unroll
    for (int i2 = 0; i2 < 2; i2++)
        #pragma unroll
        for (int hb = 0; hb < 2; hb++) {
            float s = sp[i2][hb];
            s += __shfl_xor(s, 16, 64);
            s += __shfl_xor(s, 32, 64);
            sp[i2][hb] = s;
        }
    if (g == 0) {
        #pragma unroll
        for (int i2 = 0; i2 < 2; i2++)
            #pragma unroll
            for (int hb = 0; hb < 2; hb++)
                s_buf[2 * w + i2][li + 16 * hb] = sp[i2][hb];
    }
    __syncthreads();
    #pragma unroll
    for (int h4 = 0; h4 < 4; h4++) {
        const int h = 4 * w + h4;
        const float inv = 1.0f / s_buf[li][h];
        #pragma unroll
        for (int ab = 0; ab < 2; ab++) {
            f32x4 a = accpv[h4][ab];
            uint2 o;
            o.x = pk2bf(a[0] * inv, a[1] * inv);
            o.y = pk2bf(a[2] * inv, a[3] * inv);
            *(uint2*)(out_pre + (size_t)(b * 512 + i0 + li) * 1024 + h * 32 + ab * 16 + 4 * g) = o;
        }
    }
}

// ---------------------------------------------------------------------------
// Kernel 3: out[t,b,:] = out_pre[(b,t),:] @ Wo^T + bo   (tile 128x64, BK=32)
// ---------------------------------------------------------------------------
__global__ __launch_bounds__(256) void outproj_kernel(
    const __hip_bfloat16* __restrict__ out_pre,
    const float* __restrict__ Wo, const float* __restrict__ bo,
    float* __restrict__ out)
{
    __shared__ unsigned lA[128 * 20];
    __shared__ unsigned lB[64 * 20];
    const int m0 = blockIdx.x * 128, n0 = blockIdx.y * 64;
    const int tid = threadIdx.x, lane = tid & 63, w = tid >> 6;
    const int g = lane >> 4, li = lane & 15;
    const int mw = w >> 1, nw = w & 1;

    f32x4 acc[4][2];
    const f32x4 zero4 = {0.f, 0.f, 0.f, 0.f};
    for (int mf = 0; mf < 4; mf++)
        for (int nf = 0; nf < 2; nf++) acc[mf][nf] = zero4;

    const int ar = tid >> 1, ah = tid & 1;
    const int bn = tid >> 2, bq4 = tid & 3;

    for (int k0 = 0; k0 < 1024; k0 += 32) {
        {
            const uint4* s = (const uint4*)(out_pre + (size_t)(m0 + ar) * 1024 + k0 + ah * 16);
            uint4 v0 = s[0], v1 = s[1];
            uint4* d = (uint4*)(lA + ar * 20 + ah * 8);
            d[0] = v0; d[1] = v1;
        }
        {
            const float4* s = (const float4*)(Wo + (size_t)(n0 + bn) * 1024 + k0 + bq4 * 8);
            float4 v0 = s[0], v1 = s[1];
            unsigned* d = lB + bn * 20 + bq4 * 4;
            d[0] = pk2bf(v0.x, v0.y); d[1] = pk2bf(v0.z, v0.w);
            d[2] = pk2bf(v1.x, v1.y); d[3] = pk2bf(v1.z, v1.w);
        }
        __syncthreads();
        short8 afr[4], bfr[2];
        #pragma unroll
        for (int mf = 0; mf < 4; mf++)
            afr[mf] = *(const short8*)((const char*)lA + (mw * 64 + mf * 16 + li) * 80 + g * 16);
        #pragma unroll
        for (int nf = 0; nf < 2; nf++)
            bfr[nf] = *(const short8*)((const char*)lB + (nw * 32 + nf * 16 + li) * 80 + g * 16);
        #pragma unroll
        for (int mf = 0; mf < 4; mf++)
            #pragma unroll
            for (int nf = 0; nf < 2; nf++)
                acc[mf][nf] = mfma16(afr[mf], bfr[nf], acc[mf][nf]);
        __syncthreads();
    }

    #pragma unroll
    for (int mf = 0; mf < 4; mf++) {
        #pragma unroll
        for (int nf = 0; nf < 2; nf++) {
            const int ng = n0 + nw * 32 + nf * 16 + li;
            const int mbase = m0 + mw * 64 + mf * 16 + 4 * g;
            const float bias = bo[ng];
            f32x4 a = acc[mf][nf];
            for (int r = 0; r < 4; r++) {
                const int m = mbase + r;
                const int bb2 = m >> 9, t = m & 511;
                out[(size_t)(t * 8 + bb2) * 1024 + ng] = a[r] + bias;
            }
        }
    }
}

extern "C" void kernel_launch(void* const* d_in, const int* in_sizes, int n_in,
                              void* d_out, int out_size, void* d_ws, size_t ws_size,
                              hipStream_t stream)
{
    (void)in_sizes; (void)n_in; (void)out_size; (void)ws_size;
    const float* query     = (const float*)d_in[0];
    const float* attn_bias = (const float*)d_in[1];
    const float* Wq        = (const float*)d_in[2];
    const float* bq        = (const float*)d_in[3];
    const float* Wk        = (const float*)d_in[4];
    const float* bk        = (const float*)d_in[5];
    const float* Wv        = (const float*)d_in[6];
    const float* bv        = (const float*)d_in[7];
    const float* Wt        = (const float*)d_in[8];
    const float* Wo        = (const float*)d_in[9];
    const float* bo        = (const float*)d_in[10];
    float* out = (float*)d_out;

    char* ws = (char*)d_ws;
    __hip_bfloat16* q_bf    = (__hip_bfloat16*)(ws);                          // 256 KB
    __hip_bfloat16* k_bf    = (__hip_bfloat16*)(ws + (256 << 10));            // 256 KB
    __hip_bfloat16* v_t     = (__hip_bfloat16*)(ws + (512 << 10));            // 8 MB
    __hip_bfloat16* out_pre = (__hip_bfloat16*)(ws + (512 << 10) + (8 << 20));// 8 MB

    hipLaunchKernelGGL(prep_kernel, dim3(32, 17), dim3(256), 0, stream,
                       query, Wq, bq, Wk, bk, Wv, bv, q_bf, k_bf, v_t);
    hipLaunchKernelGGL(attn_kernel, dim3(256), dim3(512), 0, stream,
                       attn_bias, Wt, q_bf, k_bf, v_t, out_pre);
    hipLaunchKernelGGL(outproj_kernel, dim3(32, 16), dim3(256), 0, stream,
                       out_pre, Wo, bo, out);
}